// Round 1
// baseline (2996.231 us; speedup 1.0000x reference)
//
#include <hip/hip_runtime.h>
#include <math.h>

constexpr int B_ = 16, C_ = 512, K_ = 64, N_ = 8192;
constexpr int NCHUNK = 1024;

// ---------------------------------------------------------------------------
// Generic per-batch 1x1-conv GEMM: Y[b] (C x N) = W (C x C) @ Xin[b] (C x N) (+bias)
// 64x64 tile, BK=16, 256 threads, 4x4 per thread.
// ---------------------------------------------------------------------------
template <bool BIAS>
__global__ __launch_bounds__(256) void conv_gemm(
    const float* __restrict__ W, const float* __restrict__ Xin,
    const float* __restrict__ bias, float* __restrict__ Y) {
  const int b  = blockIdx.z;
  const int m0 = blockIdx.y * 64;
  const int n0 = blockIdx.x * 64;
  const float* __restrict__ Xb = Xin + (size_t)b * C_ * N_;
  float* __restrict__ Yb = Y + (size_t)b * C_ * N_;

  __shared__ float As[16][64];  // [k][m]
  __shared__ float Bs[16][64];  // [k][n]

  const int tid = threadIdx.x;
  const int tx = tid & 15, ty = tid >> 4;
  const int arow = tid >> 2, ak4 = (tid & 3) << 2;
  const int bkk = tid >> 4, bn4 = (tid & 15) << 2;

  float acc[4][4] = {};

  for (int k0 = 0; k0 < C_; k0 += 16) {
    const float4 a = *reinterpret_cast<const float4*>(&W[(size_t)(m0 + arow) * C_ + k0 + ak4]);
    const float4 xv = *reinterpret_cast<const float4*>(&Xb[(size_t)(k0 + bkk) * N_ + n0 + bn4]);
    As[ak4 + 0][arow] = a.x;
    As[ak4 + 1][arow] = a.y;
    As[ak4 + 2][arow] = a.z;
    As[ak4 + 3][arow] = a.w;
    *reinterpret_cast<float4*>(&Bs[bkk][bn4]) = xv;
    __syncthreads();
#pragma unroll
    for (int kk = 0; kk < 16; ++kk) {
      const float4 av = *reinterpret_cast<const float4*>(&As[kk][ty << 2]);
      const float4 bv = *reinterpret_cast<const float4*>(&Bs[kk][tx << 2]);
      const float am[4] = {av.x, av.y, av.z, av.w};
      const float bn[4] = {bv.x, bv.y, bv.z, bv.w};
#pragma unroll
      for (int i = 0; i < 4; ++i)
#pragma unroll
        for (int j = 0; j < 4; ++j) acc[i][j] = fmaf(am[i], bn[j], acc[i][j]);
    }
    __syncthreads();
  }
#pragma unroll
  for (int i = 0; i < 4; ++i) {
    const int m = m0 + (ty << 2) + i;
    const float bb = BIAS ? bias[m] : 0.0f;
    const float4 o = {acc[i][0] + bb, acc[i][1] + bb, acc[i][2] + bb, acc[i][3] + bb};
    *reinterpret_cast<float4*>(&Yb[(size_t)m * N_ + n0 + (tx << 2)]) = o;
  }
}

// ---------------------------------------------------------------------------
// E-step: S = Xs^T @ mu (64 rows of N x all 64 K-cols), softmax over K,
// write z, accumulate colsum[b][k] = sum_n z.
// ---------------------------------------------------------------------------
__global__ __launch_bounds__(256) void estep_kernel(
    const float* __restrict__ XS, const float* __restrict__ MUsrc,
    const int mu_bstride, float* __restrict__ Z, float* __restrict__ colsum) {
  const int b  = blockIdx.y;
  const int n0 = blockIdx.x * 64;
  const float* __restrict__ Xb = XS + (size_t)b * C_ * N_;
  const float* __restrict__ Mb = MUsrc + (size_t)b * mu_bstride;

  __shared__ float As[16][64];  // [c][n]
  __shared__ float Bs[16][64];  // [c][k]
  __shared__ float cs[64];

  const int tid = threadIdx.x;
  const int tx = tid & 15, ty = tid >> 4;
  const int lkk = tid >> 4, lc4 = (tid & 15) << 2;

  float acc[4][4] = {};
  for (int c0 = 0; c0 < C_; c0 += 16) {
    const float4 xa = *reinterpret_cast<const float4*>(&Xb[(size_t)(c0 + lkk) * N_ + n0 + lc4]);
    const float4 mb = *reinterpret_cast<const float4*>(&Mb[(size_t)(c0 + lkk) * K_ + lc4]);
    *reinterpret_cast<float4*>(&As[lkk][lc4]) = xa;
    *reinterpret_cast<float4*>(&Bs[lkk][lc4]) = mb;
    __syncthreads();
#pragma unroll
    for (int kk = 0; kk < 16; ++kk) {
      const float4 av = *reinterpret_cast<const float4*>(&As[kk][ty << 2]);
      const float4 bv = *reinterpret_cast<const float4*>(&Bs[kk][tx << 2]);
      const float am[4] = {av.x, av.y, av.z, av.w};
      const float bn[4] = {bv.x, bv.y, bv.z, bv.w};
#pragma unroll
      for (int i = 0; i < 4; ++i)
#pragma unroll
        for (int j = 0; j < 4; ++j) acc[i][j] = fmaf(am[i], bn[j], acc[i][j]);
    }
    __syncthreads();
  }

  if (tid < 64) cs[tid] = 0.0f;
  __syncthreads();

  float cp[4] = {};
#pragma unroll
  for (int i = 0; i < 4; ++i) {
    // row n = n0 + ty*4 + i; spread across 16 lanes (tx) of the same wave.
    float m = fmaxf(fmaxf(acc[i][0], acc[i][1]), fmaxf(acc[i][2], acc[i][3]));
#pragma unroll
    for (int off = 1; off < 16; off <<= 1) m = fmaxf(m, __shfl_xor(m, off));
    const float p0 = __expf(acc[i][0] - m);
    const float p1 = __expf(acc[i][1] - m);
    const float p2 = __expf(acc[i][2] - m);
    const float p3 = __expf(acc[i][3] - m);
    float s = p0 + p1 + p2 + p3;
#pragma unroll
    for (int off = 1; off < 16; off <<= 1) s += __shfl_xor(s, off);
    const float inv = 1.0f / s;
    const float z0 = p0 * inv, z1 = p1 * inv, z2 = p2 * inv, z3 = p3 * inv;
    const int n = n0 + (ty << 2) + i;
    const float4 zq = {z0, z1, z2, z3};
    *reinterpret_cast<float4*>(&Z[((size_t)b * N_ + n) * K_ + (tx << 2)]) = zq;
    cp[0] += z0; cp[1] += z1; cp[2] += z2; cp[3] += z3;
  }
#pragma unroll
  for (int j = 0; j < 4; ++j) atomicAdd(&cs[(tx << 2) + j], cp[j]);
  __syncthreads();
  if (tid < 64) atomicAdd(&colsum[b * K_ + tid], cs[tid]);
}

// ---------------------------------------------------------------------------
// M-step: MU[b] += Xs[b] (C x Nchunk) @ z_ (Nchunk x K), z_ = z * rcp(colsum).
// Split-K over N with fp32 atomics (MU zeroed beforehand).
// ---------------------------------------------------------------------------
__global__ __launch_bounds__(256) void mstep_kernel(
    const float* __restrict__ XS, const float* __restrict__ Z,
    const float* __restrict__ colsum, float* __restrict__ MU) {
  const int b = blockIdx.z;
  const int c0 = blockIdx.y * 64;
  const int nbase = blockIdx.x * NCHUNK;
  const float* __restrict__ Xb = XS + (size_t)b * C_ * N_;

  __shared__ float As[16][64];  // [n][c]
  __shared__ float Bs[16][64];  // [n][k]
  __shared__ float rcp[64];

  const int tid = threadIdx.x;
  if (tid < 64) rcp[tid] = 1.0f / (1e-6f + colsum[b * K_ + tid]);
  __syncthreads();

  const int tx = tid & 15, ty = tid >> 4;
  const int arow = tid >> 2, an4 = (tid & 3) << 2;
  const int bnn = tid >> 4, bk4 = (tid & 15) << 2;

  float acc[4][4] = {};
  for (int n0 = nbase; n0 < nbase + NCHUNK; n0 += 16) {
    const float4 a = *reinterpret_cast<const float4*>(&Xb[(size_t)(c0 + arow) * N_ + n0 + an4]);
    float4 zv = *reinterpret_cast<const float4*>(&Z[((size_t)b * N_ + n0 + bnn) * K_ + bk4]);
    zv.x *= rcp[bk4 + 0];
    zv.y *= rcp[bk4 + 1];
    zv.z *= rcp[bk4 + 2];
    zv.w *= rcp[bk4 + 3];
    As[an4 + 0][arow] = a.x;
    As[an4 + 1][arow] = a.y;
    As[an4 + 2][arow] = a.z;
    As[an4 + 3][arow] = a.w;
    *reinterpret_cast<float4*>(&Bs[bnn][bk4]) = zv;
    __syncthreads();
#pragma unroll
    for (int kk = 0; kk < 16; ++kk) {
      const float4 av = *reinterpret_cast<const float4*>(&As[kk][ty << 2]);
      const float4 bv = *reinterpret_cast<const float4*>(&Bs[kk][tx << 2]);
      const float am[4] = {av.x, av.y, av.z, av.w};
      const float bn[4] = {bv.x, bv.y, bv.z, bv.w};
#pragma unroll
      for (int i = 0; i < 4; ++i)
#pragma unroll
        for (int j = 0; j < 4; ++j) acc[i][j] = fmaf(am[i], bn[j], acc[i][j]);
    }
    __syncthreads();
  }
#pragma unroll
  for (int i = 0; i < 4; ++i)
#pragma unroll
    for (int j = 0; j < 4; ++j)
      atomicAdd(&MU[((size_t)b * C_ + c0 + (ty << 2) + i) * K_ + (tx << 2) + j], acc[i][j]);
}

// ---------------------------------------------------------------------------
// Reconstruction: X2 = relu(MU (C x K) @ Z^T (K x N)), K = 64 (single shot).
// ---------------------------------------------------------------------------
__global__ __launch_bounds__(256) void x2_kernel(
    const float* __restrict__ MU, const float* __restrict__ Z,
    float* __restrict__ X2) {
  const int b = blockIdx.z;
  const int c0 = blockIdx.y * 64;
  const int n0 = blockIdx.x * 64;

  __shared__ float As[64][64];  // [k][c]
  __shared__ float Bs[64][64];  // [k][n]

  const int tid = threadIdx.x;
  const int tx = tid & 15, ty = tid >> 4;
  const int lr = tid >> 4, lk4 = (tid & 15) << 2;

#pragma unroll
  for (int it = 0; it < 4; ++it) {
    const int r = lr + it * 16;
    const float4 mv = *reinterpret_cast<const float4*>(&MU[((size_t)b * C_ + c0 + r) * K_ + lk4]);
    const float4 zv = *reinterpret_cast<const float4*>(&Z[((size_t)b * N_ + n0 + r) * K_ + lk4]);
    As[lk4 + 0][r] = mv.x;
    As[lk4 + 1][r] = mv.y;
    As[lk4 + 2][r] = mv.z;
    As[lk4 + 3][r] = mv.w;
    Bs[lk4 + 0][r] = zv.x;
    Bs[lk4 + 1][r] = zv.y;
    Bs[lk4 + 2][r] = zv.z;
    Bs[lk4 + 3][r] = zv.w;
  }
  __syncthreads();

  float acc[4][4] = {};
#pragma unroll
  for (int kk = 0; kk < 64; ++kk) {
    const float4 av = *reinterpret_cast<const float4*>(&As[kk][ty << 2]);
    const float4 bv = *reinterpret_cast<const float4*>(&Bs[kk][tx << 2]);
    const float am[4] = {av.x, av.y, av.z, av.w};
    const float bn[4] = {bv.x, bv.y, bv.z, bv.w};
#pragma unroll
    for (int i = 0; i < 4; ++i)
#pragma unroll
      for (int j = 0; j < 4; ++j) acc[i][j] = fmaf(am[i], bn[j], acc[i][j]);
  }

#pragma unroll
  for (int i = 0; i < 4; ++i) {
    const int c = c0 + (ty << 2) + i;
    const float4 o = {fmaxf(acc[i][0], 0.0f), fmaxf(acc[i][1], 0.0f),
                      fmaxf(acc[i][2], 0.0f), fmaxf(acc[i][3], 0.0f)};
    *reinterpret_cast<float4*>(&X2[((size_t)b * C_ + c) * N_ + n0 + (tx << 2)]) = o;
  }
}

// ---------------------------------------------------------------------------
// BatchNorm stats over (B, N) per channel (double accumulation).
// ---------------------------------------------------------------------------
__global__ __launch_bounds__(256) void bn_stats_kernel(
    const float* __restrict__ X3, float* __restrict__ meanp,
    float* __restrict__ rstdp) {
  const int c = blockIdx.x;
  const int tid = threadIdx.x;
  double s = 0.0, s2 = 0.0;
  for (int b = 0; b < B_; ++b) {
    const float4* p = reinterpret_cast<const float4*>(X3 + ((size_t)b * C_ + c) * N_);
    for (int i = tid; i < N_ / 4; i += 256) {
      const float4 v = p[i];
      s += (double)v.x + (double)v.y + (double)v.z + (double)v.w;
      s2 += (double)v.x * v.x + (double)v.y * v.y + (double)v.z * v.z +
            (double)v.w * v.w;
    }
  }
  __shared__ double sh[256];
  __shared__ double sh2[256];
  sh[tid] = s;
  sh2[tid] = s2;
  __syncthreads();
  for (int off = 128; off > 0; off >>= 1) {
    if (tid < off) {
      sh[tid] += sh[tid + off];
      sh2[tid] += sh2[tid + off];
    }
    __syncthreads();
  }
  if (tid == 0) {
    const double inv = 1.0 / ((double)B_ * N_);
    const double m = sh[0] * inv;
    const double var = sh2[0] * inv - m * m;
    meanp[c] = (float)m;
    rstdp[c] = (float)rsqrt(var + 1e-5);
  }
}

// ---------------------------------------------------------------------------
// y = gamma*(x3-mean)*rstd + beta + idn  (in place on OUT)
// ---------------------------------------------------------------------------
__global__ __launch_bounds__(256) void bn_apply_kernel(
    float* __restrict__ OUT, const float* __restrict__ Xin,
    const float* __restrict__ gamma, const float* __restrict__ beta,
    const float* __restrict__ meanp, const float* __restrict__ rstdp) {
  const size_t total4 = (size_t)B_ * C_ * N_ / 4;
  for (size_t i = (size_t)blockIdx.x * 256 + threadIdx.x; i < total4;
       i += (size_t)gridDim.x * 256) {
    const int c = (int)((i >> 11) & (C_ - 1));  // N/4 = 2048
    const float g = gamma[c] * rstdp[c];
    const float o = beta[c] - meanp[c] * g;
    float4 v = reinterpret_cast<const float4*>(OUT)[i];
    const float4 xi = reinterpret_cast<const float4*>(Xin)[i];
    v.x = v.x * g + o + xi.x;
    v.y = v.y * g + o + xi.y;
    v.z = v.z * g + o + xi.z;
    v.w = v.w * g + o + xi.w;
    reinterpret_cast<float4*>(OUT)[i] = v;
  }
}

// ---------------------------------------------------------------------------
extern "C" void kernel_launch(void* const* d_in, const int* in_sizes, int n_in,
                              void* d_out, int out_size, void* d_ws,
                              size_t ws_size, hipStream_t stream) {
  (void)in_sizes; (void)n_in; (void)out_size; (void)ws_size;
  const float* x     = (const float*)d_in[0];
  const float* w1    = (const float*)d_in[1];
  const float* b1    = (const float*)d_in[2];
  const float* mu0   = (const float*)d_in[3];
  const float* w2    = (const float*)d_in[4];
  const float* gamma = (const float*)d_in[5];
  const float* beta  = (const float*)d_in[6];

  float* OUT = (float*)d_out;                  // B*C*N
  float* MU  = OUT + (size_t)B_ * C_ * N_;     // B*C*K (final mu output slot)
  float* Z   = OUT;                            // z (B*N*K) lives in OUT region until x3
  float* XS  = (float*)d_ws;                   // B*C*N (xs, later reused as x2)
  float* colsum = XS + (size_t)B_ * C_ * N_;   // B*K
  float* meanp  = colsum + B_ * K_;            // C
  float* rstdp  = meanp + C_;                  // C

  const dim3 blk(256);

  // conv1: xs = w1 @ x + b1
  conv_gemm<true><<<dim3(N_ / 64, C_ / 64, B_), blk, 0, stream>>>(w1, x, b1, XS);

  // 3 EM iterations
  for (int it = 0; it < 3; ++it) {
    hipMemsetAsync(colsum, 0, B_ * K_ * sizeof(float), stream);
    estep_kernel<<<dim3(N_ / 64, B_), blk, 0, stream>>>(
        XS, it == 0 ? mu0 : MU, it == 0 ? 0 : C_ * K_, Z, colsum);
    hipMemsetAsync(MU, 0, (size_t)B_ * C_ * K_ * sizeof(float), stream);
    mstep_kernel<<<dim3(N_ / NCHUNK, C_ / 64, B_), blk, 0, stream>>>(XS, Z, colsum, MU);
  }

  // x2 = relu(mu @ z^T) into XS (xs dead)
  x2_kernel<<<dim3(N_ / 64, C_ / 64, B_), blk, 0, stream>>>(MU, Z, XS);
  // x3 = w2 @ x2 into OUT (z dead)
  conv_gemm<false><<<dim3(N_ / 64, C_ / 64, B_), blk, 0, stream>>>(w2, XS, nullptr, OUT);
  // BatchNorm stats + apply (+ residual)
  bn_stats_kernel<<<dim3(C_), blk, 0, stream>>>(OUT, meanp, rstdp);
  bn_apply_kernel<<<dim3(2048), blk, 0, stream>>>(OUT, x, gamma, beta, meanp, rstdp);
}

// Round 3
// 1304.021 us; speedup vs baseline: 2.2977x; 2.2977x over previous
//
#include <hip/hip_runtime.h>
#include <math.h>

constexpr int B_ = 16, C_ = 512, K_ = 64, N_ = 8192;
constexpr int BHALF = 8;

typedef __bf16 bf16;
typedef __bf16 bf16x4 __attribute__((ext_vector_type(4)));
typedef __bf16 bf16x8 __attribute__((ext_vector_type(8)));
typedef float f32x4 __attribute__((ext_vector_type(4)));

#define GLDS16(gp, lp)                                              \
  __builtin_amdgcn_global_load_lds(                                 \
      (const __attribute__((address_space(1))) unsigned int*)(gp),  \
      (__attribute__((address_space(3))) unsigned int*)(lp), 16, 0, 0)

__device__ __forceinline__ bf16 lo_part(float v, bf16 h) {
  return (bf16)(v - (float)h);
}

// ---------------------------------------------------------------------------
// x (BHALF,C,N) fp32 -> XT hi/lo (BHALF,N,C) bf16 planes.
// ---------------------------------------------------------------------------
__global__ __launch_bounds__(256) void transpose_split_x(
    const float* __restrict__ X, bf16* __restrict__ XTH, bf16* __restrict__ XTL) {
  const int b = blockIdx.z, c0 = blockIdx.y * 64, n0 = blockIdx.x * 64;
  __shared__ float tile[64][65];
  const int tid = threadIdx.x;
  const int rr = tid >> 4, q4 = (tid & 15) << 2;
#pragma unroll
  for (int r = 0; r < 4; ++r) {
    const int c = r * 16 + rr;
    *reinterpret_cast<float4*>(&tile[c][q4]) = *reinterpret_cast<const float4*>(
        &X[((size_t)b * C_ + c0 + c) * N_ + n0 + q4]);
  }
  __syncthreads();
#pragma unroll
  for (int r = 0; r < 4; ++r) {
    const int n = r * 16 + rr;
    bf16x4 oh, ol;
#pragma unroll
    for (int e = 0; e < 4; ++e) {
      const float v = tile[q4 + e][n];
      const bf16 h = (bf16)v;
      oh[e] = h;
      ol[e] = lo_part(v, h);
    }
    const size_t off = ((size_t)b * N_ + n0 + n) * C_ + c0 + q4;
    *reinterpret_cast<bf16x4*>(&XTH[off]) = oh;
    *reinterpret_cast<bf16x4*>(&XTL[off]) = ol;
  }
}

__global__ void cast_w_split(const float* __restrict__ W, bf16* __restrict__ H,
                             bf16* __restrict__ L) {
  const int i = blockIdx.x * 256 + threadIdx.x;
  const float v = W[i];
  const bf16 h = (bf16)v;
  H[i] = h;
  L[i] = lo_part(v, h);
}

__global__ void cast_mu0T_split(const float* __restrict__ MU0,
                                bf16* __restrict__ H, bf16* __restrict__ L) {
  const int k = blockIdx.x;
  for (int c = threadIdx.x; c < C_; c += 256) {
    const float v = MU0[c * K_ + k];
    const bf16 h = (bf16)v;
    H[k * C_ + c] = h;
    L[k * C_ + c] = lo_part(v, h);
  }
}

// ---------------------------------------------------------------------------
// conv1: xs_NC = XT . w1^T + b1, split-bf16 3-pass MFMA. 128x128 tile, BK=64.
// Outputs xs hi/lo bf16 planes.
// ---------------------------------------------------------------------------
__global__ __launch_bounds__(256) void conv1_split(
    const bf16* __restrict__ XTH, const bf16* __restrict__ XTL,
    const bf16* __restrict__ W1H, const bf16* __restrict__ W1L,
    const float* __restrict__ bias, bf16* __restrict__ XSH,
    bf16* __restrict__ XSL) {
  const int bz = blockIdx.z;
  const int m0 = blockIdx.x * 128, n0 = blockIdx.y * 128;
  const bf16* __restrict__ AH = XTH + (size_t)bz * N_ * C_;
  const bf16* __restrict__ AL = XTL + (size_t)bz * N_ * C_;

  __shared__ bf16 Ah[128][64], Al[128][64], Bh[128][64], Bl[128][64];

  const int tid = threadIdx.x, wid = tid >> 6, lane = tid & 63;
  const int lc = lane & 15, hi = lane >> 4;
  const int wm = wid >> 1, wn = wid & 1;

  f32x4 acc[4][4] = {};

  for (int k0 = 0; k0 < C_; k0 += 64) {
#pragma unroll
    for (int it = 0; it < 4; ++it) {
      const int chunk = it * 256 + tid;
      const int row = chunk >> 3, k8 = (chunk & 7) << 3;
      const size_t doff = (size_t)(it * 256 + wid * 64) * 8;
      GLDS16(AH + (size_t)(m0 + row) * C_ + k0 + k8, &Ah[0][0] + doff);
      GLDS16(AL + (size_t)(m0 + row) * C_ + k0 + k8, &Al[0][0] + doff);
      GLDS16(W1H + (size_t)(n0 + row) * C_ + k0 + k8, &Bh[0][0] + doff);
      GLDS16(W1L + (size_t)(n0 + row) * C_ + k0 + k8, &Bl[0][0] + doff);
    }
    __syncthreads();
#pragma unroll
    for (int ks = 0; ks < 2; ++ks) {
      bf16x8 ah[4], al4[4], bh[4], bl4[4];
      const int kc = (ks * 4 + hi) * 8;
#pragma unroll
      for (int i = 0; i < 4; ++i) {
        ah[i] = *reinterpret_cast<const bf16x8*>(&Ah[wm * 64 + i * 16 + lc][kc]);
        al4[i] = *reinterpret_cast<const bf16x8*>(&Al[wm * 64 + i * 16 + lc][kc]);
      }
#pragma unroll
      for (int j = 0; j < 4; ++j) {
        bh[j] = *reinterpret_cast<const bf16x8*>(&Bh[wn * 64 + j * 16 + lc][kc]);
        bl4[j] = *reinterpret_cast<const bf16x8*>(&Bl[wn * 64 + j * 16 + lc][kc]);
      }
#pragma unroll
      for (int i = 0; i < 4; ++i)
#pragma unroll
        for (int j = 0; j < 4; ++j) {
          acc[i][j] = __builtin_amdgcn_mfma_f32_16x16x32_bf16(al4[i], bh[j], acc[i][j], 0, 0, 0);
          acc[i][j] = __builtin_amdgcn_mfma_f32_16x16x32_bf16(ah[i], bl4[j], acc[i][j], 0, 0, 0);
          acc[i][j] = __builtin_amdgcn_mfma_f32_16x16x32_bf16(ah[i], bh[j], acc[i][j], 0, 0, 0);
        }
    }
    __syncthreads();
  }

#pragma unroll
  for (int j = 0; j < 4; ++j) {
    const int col = n0 + wn * 64 + j * 16 + lc;
    const float bv = bias[col];
#pragma unroll
    for (int i = 0; i < 4; ++i) {
      const int row0 = m0 + wm * 64 + i * 16 + hi * 4;
#pragma unroll
      for (int r = 0; r < 4; ++r) {
        const float v = acc[i][j][r] + bv;
        const size_t off = ((size_t)bz * N_ + row0 + r) * C_ + col;
        const bf16 h = (bf16)v;
        XSH[off] = h;
        XSL[off] = lo_part(v, h);
      }
    }
  }
}

// ---------------------------------------------------------------------------
// E-step: logits = xs . mu^T (split 3-pass), fp32 softmax over K=64,
// z hi/lo bf16 out + colsum atomics. BM=128 (4 waves x 32 rows), BK=64.
// ---------------------------------------------------------------------------
__global__ __launch_bounds__(256) void estep_split(
    const bf16* __restrict__ XSH, const bf16* __restrict__ XSL,
    const bf16* __restrict__ MTH, const bf16* __restrict__ MTL,
    size_t mustride, bf16* __restrict__ ZH, bf16* __restrict__ ZL,
    float* __restrict__ colsum) {
  const int b = blockIdx.y;
  const int m0 = blockIdx.x * 128;
  const bf16* __restrict__ AHp = XSH + (size_t)b * N_ * C_;
  const bf16* __restrict__ ALp = XSL + (size_t)b * N_ * C_;
  const bf16* __restrict__ BHp = MTH + (size_t)b * mustride;
  const bf16* __restrict__ BLp = MTL + (size_t)b * mustride;

  __shared__ bf16 Ah[128][64], Al[128][64], Bh[64][64], Bl[64][64];
  __shared__ float cs[64];

  const int tid = threadIdx.x, wid = tid >> 6, lane = tid & 63;
  const int lc = lane & 15, hi = lane >> 4;
  if (tid < 64) cs[tid] = 0.0f;

  f32x4 acc[2][4] = {};
  for (int k0 = 0; k0 < C_; k0 += 64) {
#pragma unroll
    for (int it = 0; it < 4; ++it) {
      const int chunk = it * 256 + tid;
      const int row = chunk >> 3, k8 = (chunk & 7) << 3;
      const size_t doff = (size_t)(it * 256 + wid * 64) * 8;
      GLDS16(AHp + (size_t)(m0 + row) * C_ + k0 + k8, &Ah[0][0] + doff);
      GLDS16(ALp + (size_t)(m0 + row) * C_ + k0 + k8, &Al[0][0] + doff);
    }
#pragma unroll
    for (int it = 0; it < 2; ++it) {
      const int chunk = it * 256 + tid;
      const int row = chunk >> 3, k8 = (chunk & 7) << 3;
      const size_t doff = (size_t)(it * 256 + wid * 64) * 8;
      GLDS16(BHp + (size_t)row * C_ + k0 + k8, &Bh[0][0] + doff);
      GLDS16(BLp + (size_t)row * C_ + k0 + k8, &Bl[0][0] + doff);
    }
    __syncthreads();
#pragma unroll
    for (int ks = 0; ks < 2; ++ks) {
      const int kc = (ks * 4 + hi) * 8;
      bf16x8 ah[2], al4[2], bh[4], bl4[4];
#pragma unroll
      for (int i = 0; i < 2; ++i) {
        ah[i] = *reinterpret_cast<const bf16x8*>(&Ah[wid * 32 + i * 16 + lc][kc]);
        al4[i] = *reinterpret_cast<const bf16x8*>(&Al[wid * 32 + i * 16 + lc][kc]);
      }
#pragma unroll
      for (int j = 0; j < 4; ++j) {
        bh[j] = *reinterpret_cast<const bf16x8*>(&Bh[j * 16 + lc][kc]);
        bl4[j] = *reinterpret_cast<const bf16x8*>(&Bl[j * 16 + lc][kc]);
      }
#pragma unroll
      for (int i = 0; i < 2; ++i)
#pragma unroll
        for (int j = 0; j < 4; ++j) {
          acc[i][j] = __builtin_amdgcn_mfma_f32_16x16x32_bf16(al4[i], bh[j], acc[i][j], 0, 0, 0);
          acc[i][j] = __builtin_amdgcn_mfma_f32_16x16x32_bf16(ah[i], bl4[j], acc[i][j], 0, 0, 0);
          acc[i][j] = __builtin_amdgcn_mfma_f32_16x16x32_bf16(ah[i], bh[j], acc[i][j], 0, 0, 0);
        }
    }
    __syncthreads();
  }

  float cp[4] = {0.f, 0.f, 0.f, 0.f};
#pragma unroll
  for (int i = 0; i < 2; ++i) {
#pragma unroll
    for (int r = 0; r < 4; ++r) {
      float v0 = acc[i][0][r], v1 = acc[i][1][r], v2 = acc[i][2][r], v3 = acc[i][3][r];
      float mx = fmaxf(fmaxf(v0, v1), fmaxf(v2, v3));
#pragma unroll
      for (int off = 1; off < 16; off <<= 1) mx = fmaxf(mx, __shfl_xor(mx, off));
      float p0 = __expf(v0 - mx), p1 = __expf(v1 - mx);
      float p2 = __expf(v2 - mx), p3 = __expf(v3 - mx);
      float s = p0 + p1 + p2 + p3;
#pragma unroll
      for (int off = 1; off < 16; off <<= 1) s += __shfl_xor(s, off);
      const float inv = 1.0f / s;
      p0 *= inv; p1 *= inv; p2 *= inv; p3 *= inv;
      const int n = m0 + wid * 32 + i * 16 + hi * 4 + r;
      bf16* zh = ZH + ((size_t)b * N_ + n) * K_;
      bf16* zl = ZL + ((size_t)b * N_ + n) * K_;
      const float pv[4] = {p0, p1, p2, p3};
#pragma unroll
      for (int j = 0; j < 4; ++j) {
        const bf16 h = (bf16)pv[j];
        zh[j * 16 + lc] = h;
        zl[j * 16 + lc] = lo_part(pv[j], h);
        cp[j] += pv[j];
      }
    }
  }
#pragma unroll
  for (int j = 0; j < 4; ++j) atomicAdd(&cs[j * 16 + lc], cp[j]);
  __syncthreads();
  if (tid < 64) atomicAdd(&colsum[b * K_ + tid], cs[tid]);
}

// ---------------------------------------------------------------------------
// M-step: muacc (C x K) += sum_n xs[n][c]*z[n][k], split 3-pass,
// reg-staged LDS transpose. 128 threads, tile 128c x 64k, n-chunk 1024.
// ---------------------------------------------------------------------------
__global__ __launch_bounds__(128) void mstep_split(
    const bf16* __restrict__ XSH, const bf16* __restrict__ XSL,
    const bf16* __restrict__ ZHp, const bf16* __restrict__ ZLp,
    float* __restrict__ MUACC) {
  const int b = blockIdx.z;
  const int c0 = blockIdx.y * 128;
  const int nbase = blockIdx.x * 1024;
  const bf16* __restrict__ XbH = XSH + (size_t)b * N_ * C_;
  const bf16* __restrict__ XbL = XSL + (size_t)b * N_ * C_;
  const bf16* __restrict__ ZbH = ZHp + (size_t)b * N_ * K_;
  const bf16* __restrict__ ZbL = ZLp + (size_t)b * N_ * K_;

  __shared__ bf16 Ah[128][32], Al[128][32], Bh[64][32], Bl[64][32];

  const int tid = threadIdx.x, wid = tid >> 6, lane = tid & 63;
  const int lc = lane & 15, hi = lane >> 4;

  f32x4 acc[4][4] = {};
  for (int n0 = nbase; n0 < nbase + 1024; n0 += 32) {
#pragma unroll
    for (int it = 0; it < 4; ++it) {
      const int chunk = it * 128 + tid;
      const int nn = chunk & 31, c8 = (chunk >> 5) * 8;
      const bf16x8 vh = *reinterpret_cast<const bf16x8*>(
          &XbH[(size_t)(n0 + nn) * C_ + c0 + c8]);
      const bf16x8 vl = *reinterpret_cast<const bf16x8*>(
          &XbL[(size_t)(n0 + nn) * C_ + c0 + c8]);
#pragma unroll
      for (int e = 0; e < 8; ++e) {
        Ah[c8 + e][nn] = vh[e];
        Al[c8 + e][nn] = vl[e];
      }
    }
#pragma unroll
    for (int it = 0; it < 2; ++it) {
      const int chunk = it * 128 + tid;
      const int nn = chunk & 31, k8 = (chunk >> 5) * 8;
      const bf16x8 vh = *reinterpret_cast<const bf16x8*>(
          &ZbH[(size_t)(n0 + nn) * K_ + k8]);
      const bf16x8 vl = *reinterpret_cast<const bf16x8*>(
          &ZbL[(size_t)(n0 + nn) * K_ + k8]);
#pragma unroll
      for (int e = 0; e < 8; ++e) {
        Bh[k8 + e][nn] = vh[e];
        Bl[k8 + e][nn] = vl[e];
      }
    }
    __syncthreads();
    bf16x8 ah[4], al4[4], bh[4], bl4[4];
#pragma unroll
    for (int i = 0; i < 4; ++i) {
      ah[i] = *reinterpret_cast<const bf16x8*>(&Ah[wid * 64 + i * 16 + lc][hi * 8]);
      al4[i] = *reinterpret_cast<const bf16x8*>(&Al[wid * 64 + i * 16 + lc][hi * 8]);
    }
#pragma unroll
    for (int j = 0; j < 4; ++j) {
      bh[j] = *reinterpret_cast<const bf16x8*>(&Bh[j * 16 + lc][hi * 8]);
      bl4[j] = *reinterpret_cast<const bf16x8*>(&Bl[j * 16 + lc][hi * 8]);
    }
#pragma unroll
    for (int i = 0; i < 4; ++i)
#pragma unroll
      for (int j = 0; j < 4; ++j) {
        acc[i][j] = __builtin_amdgcn_mfma_f32_16x16x32_bf16(al4[i], bh[j], acc[i][j], 0, 0, 0);
        acc[i][j] = __builtin_amdgcn_mfma_f32_16x16x32_bf16(ah[i], bl4[j], acc[i][j], 0, 0, 0);
        acc[i][j] = __builtin_amdgcn_mfma_f32_16x16x32_bf16(ah[i], bh[j], acc[i][j], 0, 0, 0);
      }
    __syncthreads();
  }
#pragma unroll
  for (int i = 0; i < 4; ++i) {
    const int c = c0 + wid * 64 + i * 16 + hi * 4;
#pragma unroll
    for (int r = 0; r < 4; ++r)
#pragma unroll
      for (int j = 0; j < 4; ++j)
        atomicAdd(&MUACC[((size_t)b * C_ + c + r) * K_ + j * 16 + lc], acc[i][j][r]);
  }
}

// ---------------------------------------------------------------------------
// finalize mu: v = muacc/(1e-6+colsum); emit muT hi/lo (K,C), mu hi (C,K),
// optional fp32 mu out.
// ---------------------------------------------------------------------------
__global__ void finalize_mu(const float* __restrict__ MUACC,
                            const float* __restrict__ colsum,
                            bf16* __restrict__ MUTH, bf16* __restrict__ MUTL,
                            bf16* __restrict__ MUH, float* __restrict__ muout) {
  const int idx = blockIdx.x * 256 + threadIdx.x;  // B*C*K
  const int k = idx & (K_ - 1);
  const int c = (idx >> 6) & (C_ - 1);
  const int b = idx >> 15;
  const float v = MUACC[idx] / (1e-6f + colsum[b * K_ + k]);
  const bf16 h = (bf16)v;
  MUH[idx] = h;
  MUTH[((size_t)b * K_ + k) * C_ + c] = h;
  MUTL[((size_t)b * K_ + k) * C_ + c] = lo_part(v, h);
  if (muout) muout[idx] = v;
}

// ---------------------------------------------------------------------------
// x2_NC = relu(z . mu^T), plain bf16, single K=64 tile. 128x128 tile.
// ---------------------------------------------------------------------------
__global__ __launch_bounds__(256) void x2_plain(
    const bf16* __restrict__ ZHp, const bf16* __restrict__ MUHp,
    bf16* __restrict__ X2) {
  const int b = blockIdx.z;
  const int m0 = blockIdx.x * 128, n0 = blockIdx.y * 128;
  const bf16* __restrict__ Ab = ZHp + (size_t)b * N_ * K_;
  const bf16* __restrict__ Bb = MUHp + (size_t)b * C_ * K_;

  __shared__ bf16 As[128][64], Bs[128][64];

  const int tid = threadIdx.x, wid = tid >> 6, lane = tid & 63;
  const int lc = lane & 15, hi = lane >> 4;
  const int wm = wid >> 1, wn = wid & 1;

  f32x4 acc[4][4] = {};
#pragma unroll
  for (int it = 0; it < 4; ++it) {
    const int chunk = it * 256 + tid;
    const int row = chunk >> 3, k8 = (chunk & 7) << 3;
    const size_t doff = (size_t)(it * 256 + wid * 64) * 8;
    GLDS16(Ab + (size_t)(m0 + row) * K_ + k8, &As[0][0] + doff);
    GLDS16(Bb + (size_t)(n0 + row) * K_ + k8, &Bs[0][0] + doff);
  }
  __syncthreads();
#pragma unroll
  for (int ks = 0; ks < 2; ++ks) {
    const int kc = (ks * 4 + hi) * 8;
    bf16x8 af[4], bg[4];
#pragma unroll
    for (int i = 0; i < 4; ++i)
      af[i] = *reinterpret_cast<const bf16x8*>(&As[wm * 64 + i * 16 + lc][kc]);
#pragma unroll
    for (int j = 0; j < 4; ++j)
      bg[j] = *reinterpret_cast<const bf16x8*>(&Bs[wn * 64 + j * 16 + lc][kc]);
#pragma unroll
    for (int i = 0; i < 4; ++i)
#pragma unroll
      for (int j = 0; j < 4; ++j)
        acc[i][j] = __builtin_amdgcn_mfma_f32_16x16x32_bf16(af[i], bg[j], acc[i][j], 0, 0, 0);
  }

#pragma unroll
  for (int j = 0; j < 4; ++j) {
    const int col = n0 + wn * 64 + j * 16 + lc;
#pragma unroll
    for (int i = 0; i < 4; ++i) {
      const int row0 = m0 + wm * 64 + i * 16 + hi * 4;
#pragma unroll
      for (int r = 0; r < 4; ++r)
        X2[((size_t)b * N_ + row0 + r) * C_ + col] = (bf16)fmaxf(acc[i][j][r], 0.0f);
    }
  }
}

// ---------------------------------------------------------------------------
// conv2: x3 = w2 . x2 -> fp32 OUT (B,C,N). Plain bf16 NT GEMM.
// ---------------------------------------------------------------------------
__global__ __launch_bounds__(256) void conv2_plain(
    const bf16* __restrict__ W2H, const bf16* __restrict__ X2,
    float* __restrict__ OUT) {
  const int b = blockIdx.z;
  const int m0 = blockIdx.x * 128, n0 = blockIdx.y * 128;
  const bf16* __restrict__ Bb = X2 + (size_t)b * N_ * C_;

  __shared__ bf16 As[128][64], Bs[128][64];

  const int tid = threadIdx.x, wid = tid >> 6, lane = tid & 63;
  const int lc = lane & 15, hi = lane >> 4;
  const int wm = wid >> 1, wn = wid & 1;

  f32x4 acc[4][4] = {};
  for (int k0 = 0; k0 < C_; k0 += 64) {
#pragma unroll
    for (int it = 0; it < 4; ++it) {
      const int chunk = it * 256 + tid;
      const int row = chunk >> 3, k8 = (chunk & 7) << 3;
      const size_t doff = (size_t)(it * 256 + wid * 64) * 8;
      GLDS16(W2H + (size_t)(m0 + row) * C_ + k0 + k8, &As[0][0] + doff);
      GLDS16(Bb + (size_t)(n0 + row) * C_ + k0 + k8, &Bs[0][0] + doff);
    }
    __syncthreads();
#pragma unroll
    for (int ks = 0; ks < 2; ++ks) {
      const int kc = (ks * 4 + hi) * 8;
      bf16x8 af[4], bg[4];
#pragma unroll
      for (int i = 0; i < 4; ++i)
        af[i] = *reinterpret_cast<const bf16x8*>(&As[wm * 64 + i * 16 + lc][kc]);
#pragma unroll
      for (int j = 0; j < 4; ++j)
        bg[j] = *reinterpret_cast<const bf16x8*>(&Bs[wn * 64 + j * 16 + lc][kc]);
#pragma unroll
      for (int i = 0; i < 4; ++i)
#pragma unroll
        for (int j = 0; j < 4; ++j)
          acc[i][j] = __builtin_amdgcn_mfma_f32_16x16x32_bf16(af[i], bg[j], acc[i][j], 0, 0, 0);
    }
    __syncthreads();
  }

#pragma unroll
  for (int j = 0; j < 4; ++j) {
    const int col = n0 + wn * 64 + j * 16 + lc;  // n index
#pragma unroll
    for (int i = 0; i < 4; ++i) {
      const int row0 = m0 + wm * 64 + i * 16 + hi * 4;  // o channel
#pragma unroll
      for (int r = 0; r < 4; ++r)
        OUT[((size_t)b * C_ + row0 + r) * N_ + col] = acc[i][j][r];
    }
  }
}

// ---------------------------------------------------------------------------
// BatchNorm stats + apply (fp32, verified in round 1).
// ---------------------------------------------------------------------------
__global__ __launch_bounds__(256) void bn_stats_kernel(
    const float* __restrict__ X3, float* __restrict__ meanp, float* __restrict__ rstdp) {
  const int c = blockIdx.x;
  const int tid = threadIdx.x;
  double s = 0.0, s2 = 0.0;
  for (int b = 0; b < B_; ++b) {
    const float4* p = reinterpret_cast<const float4*>(X3 + ((size_t)b * C_ + c) * N_);
    for (int i = tid; i < N_ / 4; i += 256) {
      const float4 v = p[i];
      s += (double)v.x + (double)v.y + (double)v.z + (double)v.w;
      s2 += (double)v.x * v.x + (double)v.y * v.y + (double)v.z * v.z + (double)v.w * v.w;
    }
  }
  __shared__ double sh[256];
  __shared__ double sh2[256];
  sh[tid] = s; sh2[tid] = s2;
  __syncthreads();
  for (int off = 128; off > 0; off >>= 1) {
    if (tid < off) { sh[tid] += sh[tid + off]; sh2[tid] += sh2[tid + off]; }
    __syncthreads();
  }
  if (tid == 0) {
    const double inv = 1.0 / ((double)B_ * N_);
    const double m = sh[0] * inv;
    const double var = sh2[0] * inv - m * m;
    meanp[c] = (float)m;
    rstdp[c] = (float)rsqrt(var + 1e-5);
  }
}

__global__ __launch_bounds__(256) void bn_apply_kernel(
    float* __restrict__ OUT, const float* __restrict__ Xin,
    const float* __restrict__ gamma, const float* __restrict__ beta,
    const float* __restrict__ meanp, const float* __restrict__ rstdp) {
  const size_t total4 = (size_t)B_ * C_ * N_ / 4;
  for (size_t i = (size_t)blockIdx.x * 256 + threadIdx.x; i < total4;
       i += (size_t)gridDim.x * 256) {
    const int c = (int)((i >> 11) & (C_ - 1));
    const float g = gamma[c] * rstdp[c];
    const float o = beta[c] - meanp[c] * g;
    float4 v = reinterpret_cast<const float4*>(OUT)[i];
    const float4 xi = reinterpret_cast<const float4*>(Xin)[i];
    v.x = v.x * g + o + xi.x;
    v.y = v.y * g + o + xi.y;
    v.z = v.z * g + o + xi.z;
    v.w = v.w * g + o + xi.w;
    reinterpret_cast<float4*>(OUT)[i] = v;
  }
}

// ---------------------------------------------------------------------------
extern "C" void kernel_launch(void* const* d_in, const int* in_sizes, int n_in,
                              void* d_out, int out_size, void* d_ws,
                              size_t ws_size, hipStream_t stream) {
  (void)in_sizes; (void)n_in; (void)out_size; (void)ws_size;
  const float* x     = (const float*)d_in[0];
  const float* w1    = (const float*)d_in[1];
  const float* b1    = (const float*)d_in[2];
  const float* mu0   = (const float*)d_in[3];
  const float* w2    = (const float*)d_in[4];
  const float* gamma = (const float*)d_in[5];
  const float* beta  = (const float*)d_in[6];

  // d_out: xs hi/lo planes live here until conv2 overwrites with fp32 x3/out.
  bf16* XSH = (bf16*)d_out;
  bf16* XSL = XSH + (size_t)B_ * N_ * C_;
  float* OUT = (float*)d_out;
  float* MUOUT = OUT + (size_t)B_ * C_ * N_;

  // d_ws layout
  bf16* XTH = (bf16*)d_ws;                          // BHALF*N*C
  bf16* XTL = XTH + (size_t)BHALF * N_ * C_;        // BHALF*N*C
  bf16* X2b = XTH;                                  // alias after conv1 (B*N*C)
  bf16* ZH  = XTH + (size_t)B_ * N_ * C_;           // B*N*K
  bf16* ZL  = ZH + (size_t)B_ * N_ * K_;
  bf16* W1H = ZL + (size_t)B_ * N_ * K_;
  bf16* W1L = W1H + C_ * C_;
  bf16* W2H = W1L + C_ * C_;
  bf16* W2L = W2H + C_ * C_;
  bf16* MT0H = W2L + C_ * C_;                       // K*C
  bf16* MT0L = MT0H + K_ * C_;
  bf16* MUTH = MT0L + K_ * C_;                      // B*K*C
  bf16* MUTL = MUTH + (size_t)B_ * K_ * C_;
  bf16* MUH  = MUTL + (size_t)B_ * K_ * C_;         // B*C*K
  float* MUACC = (float*)(MUH + (size_t)B_ * C_ * K_);
  float* colsum = MUACC + (size_t)B_ * C_ * K_;
  float* meanp = colsum + B_ * K_;
  float* rstdp = meanp + C_;

  const dim3 blk(256);

  cast_w_split<<<dim3(C_ * C_ / 256), blk, 0, stream>>>(w1, W1H, W1L);
  cast_w_split<<<dim3(C_ * C_ / 256), blk, 0, stream>>>(w2, W2H, W2L);
  cast_mu0T_split<<<dim3(K_), blk, 0, stream>>>(mu0, MT0H, MT0L);

  for (int half = 0; half < 2; ++half) {
    const float* xh = x + (size_t)half * BHALF * C_ * N_;
    transpose_split_x<<<dim3(N_ / 64, C_ / 64, BHALF), blk, 0, stream>>>(xh, XTH, XTL);
    conv1_split<<<dim3(N_ / 128, C_ / 128, BHALF), blk, 0, stream>>>(
        XTH, XTL, W1H, W1L, b1,
        XSH + (size_t)half * BHALF * N_ * C_, XSL + (size_t)half * BHALF * N_ * C_);
  }

  for (int it = 0; it < 3; ++it) {
    hipMemsetAsync(colsum, 0, B_ * K_ * sizeof(float), stream);
    estep_split<<<dim3(N_ / 128, B_), blk, 0, stream>>>(
        XSH, XSL, it == 0 ? MT0H : MUTH, it == 0 ? MT0L : MUTL,
        it == 0 ? 0 : (size_t)K_ * C_, ZH, ZL, colsum);
    hipMemsetAsync(MUACC, 0, (size_t)B_ * C_ * K_ * sizeof(float), stream);
    mstep_split<<<dim3(N_ / 1024, C_ / 128, B_), dim3(128), 0, stream>>>(
        XSH, XSL, ZH, ZL, MUACC);
    finalize_mu<<<dim3(B_ * C_ * K_ / 256), blk, 0, stream>>>(
        MUACC, colsum, MUTH, MUTL, MUH, it == 2 ? MUOUT : nullptr);
  }

  x2_plain<<<dim3(N_ / 128, C_ / 128, B_), blk, 0, stream>>>(ZH, MUH, X2b);
  conv2_plain<<<dim3(C_ / 128, N_ / 128, B_), blk, 0, stream>>>(W2H, X2b, OUT);
  bn_stats_kernel<<<dim3(C_), blk, 0, stream>>>(OUT, meanp, rstdp);
  bn_apply_kernel<<<dim3(2048), blk, 0, stream>>>(OUT, x, gamma, beta, meanp, rstdp);
}